// Round 10
// baseline (575.819 us; speedup 1.0000x reference)
//
#include <hip/hip_runtime.h>
#include <hip/hip_cooperative_groups.h>
#include <math.h>

namespace cg = cooperative_groups;

#define N_ATOMS 8000
#define N_RES   2000
#define KNN     15
#define KSEG    4                // kept per segment (top-4, incl. self in own segment)
#define NSEG    64
#define SEGLEN  (N_ATOMS/NSEG)   // 125
#define N_EDGES (N_ATOMS*KNN)    // 120000
#define BE      64               // edges/instances per MFMA block
#define SX      136              // LDS X row stride (elements)
#define EB      (N_EDGES/BE)     // 1875 edge tiles
#define AB      ((5*N_RES + BE-1)/BE) // 157 angle tiles
#define KNN_TILES 2048           // 32 x-tiles * 64 segments
#define SETUP_ITEMS (24000+192000+8192+16384+16384+4096+16384)  // 277440
#define SETUP_TILES ((SETUP_ITEMS+255)/256)                     // 1084

typedef unsigned long long u64;
typedef unsigned int u32;
typedef unsigned short u16;
typedef __attribute__((ext_vector_type(8))) short bf16x8;
typedef __attribute__((ext_vector_type(4))) float f32x4;

__device__ __forceinline__ float fast_tanh(float x){
  float e = __expf(2.0f*x);
  return 1.0f - 2.0f*__builtin_amdgcn_rcpf(e+1.0f);
}
__device__ __forceinline__ u32 f2bf(float x){
  u32 b = __float_as_uint(x);
  return (b + 0x7FFFu + ((b>>16)&1u)) >> 16;
}
__device__ __forceinline__ u32 cvt_pk_bf16(float lo, float hi){
  u32 d;
  asm("v_cvt_pk_bf16_f32 %0, %1, %2" : "=v"(d) : "v"(lo), "v"(hi));
  return d;
}
__device__ __forceinline__ u32 med3_u32(u32 a, u32 b, u32 c){
  u32 d;
  asm("v_med3_u32 %0, %1, %2, %3" : "=v"(d) : "v"(a), "v"(b), "v"(c));
  return d;
}
__device__ __forceinline__ void angle_idx(int t, int ri, int& i1, int& i2, int& i3, int& central){
  int a1,a2,a3,ar;
  switch (t){
    case 0: a1=0;a2=1;a3=2;ar=0; break;
    case 1: a1=1;a2=2;a3=0;ar=1; break;
    case 2: a1=2;a2=0;a3=1;ar=2; break;
    case 3: a1=0;a2=1;a3=3;ar=0; break;
    default: a1=2;a2=1;a3=3;ar=0; break;
  }
  i1 = ri*4 + a1;
  i2 = (ri + ((ar==2)?1:0))*4 + a2;
  i3 = (ri + ((ar>=1)?1:0))*4 + a3;
  central = (t==1) ? (ri*4+2) : ((t==2) ? ((ri+1)*4) : (ri*4+1));
}

struct MegaArgs {
  const float *coords_in, *vels_in, *temp, *node_f;
  const float *dW1, *dW2, *dW3, *aW1, *aW2;
  const int* nsteps;
  const float* dtp;
  float *coordsA, *vels, *accs_last, *atom_accs;
  u32* keys; u16* nfb;
  u16 *p1, *p2, *p3, *pa1, *pa2;
  const float *db1, *db2, *db3, *dW4, *db4, *ab1, *ab2, *aW3, *ab3;
  int* recv; float* forcesE;
  const float* masses;
  float* out_coords; float* out_loss;
};

// ---------------- phase -1a: KNN partial tile (with fused step-1 pos update)
__device__ void knn_tile(const MegaArgs& A, int tk, int tid, char* SMraw){
  float4* sj4 = (float4*)SMraw;
  int seg = tk >> 5;
  int j0 = seg*SEGLEN;
  float ts = A.temp[0];
  float dt = A.dtp[0];
  if (tid < SEGLEN){
    int j = j0 + tid;
    float x = A.coords_in[j*3+0] + A.vels_in[j*3+0]*ts*dt;
    float y = A.coords_in[j*3+1] + A.vels_in[j*3+1]*ts*dt;
    float z = A.coords_in[j*3+2] + A.vels_in[j*3+2]*ts*dt;
    sj4[tid] = make_float4(x, y, z, 0.0f);
  }
  __syncthreads();
  int atom = (tk & 31)*256 + tid;
  if (atom >= N_ATOMS) return;
  float vx = A.vels_in[atom*3+0]*ts, vy = A.vels_in[atom*3+1]*ts, vz = A.vels_in[atom*3+2]*ts;
  float cx = A.coords_in[atom*3+0] + vx*dt;
  float cy = A.coords_in[atom*3+1] + vy*dt;
  float cz = A.coords_in[atom*3+2] + vz*dt;
  if (seg == 0){
    A.coordsA[atom*3+0] = cx; A.coordsA[atom*3+1] = cy; A.coordsA[atom*3+2] = cz;
    A.vels[atom*3+0] = vx; A.vels[atom*3+1] = vy; A.vels[atom*3+2] = vz;
  }
  u32 b0 = 0xFFFFFFFFu, b1 = 0xFFFFFFFFu, b2 = 0xFFFFFFFFu, b3 = 0xFFFFFFFFu;
  #pragma unroll 5
  for (int t = 0; t < SEGLEN; ++t){
    float4 s = sj4[t];
    float dx = cx - s.x, dy = cy - s.y, dz = cz - s.z;
    float d2 = dx*dx + dy*dy + dz*dz;
    // self included: d2=0 -> global min key, popped (and discarded) at merge r=0
    u32 key = (__float_as_uint(d2) & 0xFFFFE000u) | (u32)(j0 + t);
    b3 = med3_u32(key, b2, b3);
    b2 = med3_u32(key, b1, b2);
    b1 = med3_u32(key, b0, b1);
    b0 = min(b0, key);
  }
  *(uint4*)(A.keys + ((size_t)atom*NSEG + seg)*KSEG) = make_uint4(b0,b1,b2,b3);
}

// ---------------- phase -1b: setup/pack tile
__device__ void setup_tile(const MegaArgs& A, int st, int tid){
  int t = st*256 + tid;
  if (t < 24000){
    A.accs_last[t] = 0.0f;
    A.atom_accs[t] = 0.0f;
    return;
  }
  t -= 24000;
  if (t < 192000){ A.nfb[t] = (u16)f2bf(A.node_f[t]); return; }
  t -= 192000;
  if (t < 8192){   // dW1: 50x128, K padded to 64 (2 ksteps), 8 mtiles
    int i = t&7, lane = (t>>3)&63, ks = (t>>9)&1, mt = t>>10;
    int n = mt*16 + (lane&15), k = ks*32 + ((lane>>4)&3)*8 + i;
    A.p1[t] = (k < 50) ? (u16)f2bf(A.dW1[k*128+n]) : (u16)0;
    return;
  }
  t -= 8192;
  if (t < 16384){  // dW2
    int i = t&7, lane = (t>>3)&63, ks = (t>>9)&3, mt = t>>11;
    int n = mt*16 + (lane&15), k = ks*32 + ((lane>>4)&3)*8 + i;
    A.p2[t] = (u16)f2bf(A.dW2[k*128+n]);
    return;
  }
  t -= 16384;
  if (t < 16384){  // dW3
    int i = t&7, lane = (t>>3)&63, ks = (t>>9)&3, mt = t>>11;
    int n = mt*16 + (lane&15), k = ks*32 + ((lane>>4)&3)*8 + i;
    A.p3[t] = (u16)f2bf(A.dW3[k*128+n]);
    return;
  }
  t -= 16384;
  if (t < 4096){   // aW1: 25x128 padded to K=32
    int i = t&7, lane = (t>>3)&63, mt = t>>9;
    int n = mt*16 + (lane&15), k = ((lane>>4)&3)*8 + i;
    A.pa1[t] = (k < 25) ? (u16)f2bf(A.aW1[k*128+n]) : (u16)0;
    return;
  }
  t -= 4096;
  if (t < 16384){  // aW2
    int i = t&7, lane = (t>>3)&63, ks = (t>>9)&3, mt = t>>11;
    int n = mt*16 + (lane&15), k = ks*32 + ((lane>>4)&3)*8 + i;
    A.pa2[t] = (u16)f2bf(A.aW2[k*128+n]);
  }
}

// ---------------- phase -1c: loss
__device__ void loss_block(const MegaArgs& A, int tid, char* SMraw){
  float* red = (float*)SMraw;
  float s = 0.0f;
  for (int t = tid; t < N_ATOMS*3; t += 256){
    float v = A.vels_in[t]; s += v*v;
  }
  red[tid] = s; __syncthreads();
  for (int o = 128; o > 0; o >>= 1){
    if (tid < o) red[tid] += red[tid+o];
    __syncthreads();
  }
  if (tid == 0){
    float scale = A.dtp[0] * (float)A.nsteps[0] * A.temp[0];
    A.out_loss[0] = scale * sqrtf(red[0] / (float)N_ATOMS);
  }
}

// ---------------- phase 0: KNN merge (wave/atom; 16 pops, r=0 = self, discarded)
__device__ void merge_atoms(const MegaArgs& A, int bid, int nb, int tid){
  int w = tid >> 6, lane = tid & 63;
  for (int a0 = bid*4; a0 < N_ATOMS; a0 += nb*4){
    int atom = a0 + w;
    if (atom >= N_ATOMS) continue;
    uint4 k4 = *(const uint4*)(A.keys + (size_t)atom*(NSEG*KSEG) + lane*KSEG);
    u32 c0=k4.x, c1=k4.y, c2=k4.z, c3=k4.w;
    for (int r = 0; r < 16; ++r){
      u32 m = c0;
      #pragma unroll
      for (int off = 1; off < 64; off <<= 1)
        m = min(m, (u32)__shfl_xor((int)m, off, 64));
      if (r > 0 && lane == 0) A.recv[atom*KNN + (r-1)] = (int)(m & 0x1FFFu);
      u64 win = __ballot(c0 == m);
      int first = (int)__ffsll((unsigned long long)win) - 1;
      if (lane == first){
        c0=c1; c1=c2; c2=c3; c3=0xFFFFFFFFu;
      }
    }
  }
}

// ---------------- force tile: [0,EB) edge MLP, [EB,EB+AB) angle MLP
__device__ void force_tile(const MegaArgs& A, int tile, int tid, char* SM){
  int lane = tid & 63;
  int w = tid >> 6;
  int eh = w >> 1, nh = w & 1;
  int l15 = lane & 15, lg = lane >> 4;

  f32x4 acc[4][2];
  bf16x8 wf[4][4];

  if (tile < EB){
    // ---------------- EDGE PATH ----------------
    u16 (*X0)[SX] = (u16(*)[SX])SM;                       // 17408 B
    u16 (*X1)[SX] = (u16(*)[SX])(SM + 17408);             // 17408 B
    float (*ndS)[3] = (float(*)[3])(SM + 34816);          // 768 B
    float (*fpart)[BE] = (float(*)[BE])(SM + 35584);      // 512 B
    int E0 = tile * BE;

    {
      int e = tid >> 2, q = tid & 3;
      int E = E0 + e;
      int i = E / 15;
      int r = A.recv[E];
      if (q < 3){
        int c0 = q*2, c1 = q*2+1;
        int a0 = (c0 < 3) ? i : r, o0 = (c0 % 3)*8;
        int a1 = (c1 < 3) ? i : r, o1 = (c1 % 3)*8;
        uint4 v0 = *(const uint4*)(A.nfb + a0*24 + o0);
        uint4 v1 = *(const uint4*)(A.nfb + a1*24 + o1);
        *(uint4*)&X0[e][c0*8] = v0;
        *(uint4*)&X0[e][c1*8] = v1;
      } else {
        float dx = A.coordsA[i*3+0] - A.coordsA[r*3+0];
        float dy = A.coordsA[i*3+1] - A.coordsA[r*3+1];
        float dz = A.coordsA[i*3+2] - A.coordsA[r*3+2];
        float dist = sqrtf(dx*dx + dy*dy + dz*dz);
        float dn = fmaxf(dist, 0.01f);
        ndS[e][0] = dx/dn; ndS[e][1] = dy/dn; ndS[e][2] = dz/dn;
        float seq = fminf(fabsf((float)((i>>2) - (r>>2)))*0.2f, 1.0f);
        X0[e][48] = (u16)f2bf(dist);
        X0[e][49] = (u16)f2bf(seq);
        #pragma unroll
        for (int k = 50; k < 64; k += 2) *(u32*)&X0[e][k] = 0u;
      }
    }
    __syncthreads();

    // Layer 1: K=64, X0 -> X1
    #pragma unroll
    for (int mt = 0; mt < 4; ++mt)
      #pragma unroll
      for (int ks = 0; ks < 2; ++ks)
        wf[mt][ks] = *(const bf16x8*)(A.p1 + (size_t)(((nh*4+mt)*2 + ks)*64 + lane)*8);
    #pragma unroll
    for (int mt = 0; mt < 4; ++mt){
      f32x4 b = *(const f32x4*)(A.db1 + nh*64 + mt*16 + lg*4);
      acc[mt][0] = b; acc[mt][1] = b;
    }
    #pragma unroll
    for (int ks = 0; ks < 2; ++ks)
      #pragma unroll
      for (int nt = 0; nt < 2; ++nt){
        bf16x8 x = *(const bf16x8*)&X0[eh*32 + nt*16 + l15][ks*32 + lg*8];
        #pragma unroll
        for (int mt = 0; mt < 4; ++mt)
          acc[mt][nt] = __builtin_amdgcn_mfma_f32_16x16x32_bf16(wf[mt][ks], x, acc[mt][nt], 0, 0, 0);
      }
    #pragma unroll
    for (int mt = 0; mt < 4; ++mt)
      #pragma unroll
      for (int nt = 0; nt < 2; ++nt){
        uint2 pk;
        pk.x = cvt_pk_bf16(fast_tanh(acc[mt][nt][0]), fast_tanh(acc[mt][nt][1]));
        pk.y = cvt_pk_bf16(fast_tanh(acc[mt][nt][2]), fast_tanh(acc[mt][nt][3]));
        *(uint2*)&X1[eh*32 + nt*16 + l15][nh*64 + mt*16 + lg*4] = pk;
      }
    __syncthreads();

    // Layer 2: K=128, X1 -> X0
    #pragma unroll
    for (int mt = 0; mt < 4; ++mt)
      #pragma unroll
      for (int ks = 0; ks < 4; ++ks)
        wf[mt][ks] = *(const bf16x8*)(A.p2 + (size_t)(((nh*4+mt)*4 + ks)*64 + lane)*8);
    #pragma unroll
    for (int mt = 0; mt < 4; ++mt){
      f32x4 b = *(const f32x4*)(A.db2 + nh*64 + mt*16 + lg*4);
      acc[mt][0] = b; acc[mt][1] = b;
    }
    #pragma unroll
    for (int ks = 0; ks < 4; ++ks)
      #pragma unroll
      for (int nt = 0; nt < 2; ++nt){
        bf16x8 x = *(const bf16x8*)&X1[eh*32 + nt*16 + l15][ks*32 + lg*8];
        #pragma unroll
        for (int mt = 0; mt < 4; ++mt)
          acc[mt][nt] = __builtin_amdgcn_mfma_f32_16x16x32_bf16(wf[mt][ks], x, acc[mt][nt], 0, 0, 0);
      }
    #pragma unroll
    for (int mt = 0; mt < 4; ++mt)
      #pragma unroll
      for (int nt = 0; nt < 2; ++nt){
        uint2 pk;
        pk.x = cvt_pk_bf16(fast_tanh(acc[mt][nt][0]), fast_tanh(acc[mt][nt][1]));
        pk.y = cvt_pk_bf16(fast_tanh(acc[mt][nt][2]), fast_tanh(acc[mt][nt][3]));
        *(uint2*)&X0[eh*32 + nt*16 + l15][nh*64 + mt*16 + lg*4] = pk;
      }
    __syncthreads();

    // Layer 3: K=128, X0 -> regs
    #pragma unroll
    for (int mt = 0; mt < 4; ++mt)
      #pragma unroll
      for (int ks = 0; ks < 4; ++ks)
        wf[mt][ks] = *(const bf16x8*)(A.p3 + (size_t)(((nh*4+mt)*4 + ks)*64 + lane)*8);
    #pragma unroll
    for (int mt = 0; mt < 4; ++mt){
      f32x4 b = *(const f32x4*)(A.db3 + nh*64 + mt*16 + lg*4);
      acc[mt][0] = b; acc[mt][1] = b;
    }
    #pragma unroll
    for (int ks = 0; ks < 4; ++ks)
      #pragma unroll
      for (int nt = 0; nt < 2; ++nt){
        bf16x8 x = *(const bf16x8*)&X0[eh*32 + nt*16 + l15][ks*32 + lg*8];
        #pragma unroll
        for (int mt = 0; mt < 4; ++mt)
          acc[mt][nt] = __builtin_amdgcn_mfma_f32_16x16x32_bf16(wf[mt][ks], x, acc[mt][nt], 0, 0, 0);
      }

    // Layer 4
    float pe0 = 0.0f, pe1 = 0.0f;
    #pragma unroll
    for (int mt = 0; mt < 4; ++mt){
      f32x4 w4 = *(const f32x4*)(A.dW4 + nh*64 + mt*16 + lg*4);
      #pragma unroll
      for (int r = 0; r < 4; ++r){
        pe0 += fast_tanh(acc[mt][0][r]) * w4[r];
        pe1 += fast_tanh(acc[mt][1][r]) * w4[r];
      }
    }
    pe0 += __shfl_xor(pe0, 16, 64); pe0 += __shfl_xor(pe0, 32, 64);
    pe1 += __shfl_xor(pe1, 16, 64); pe1 += __shfl_xor(pe1, 32, 64);
    if (lg == 0){
      fpart[nh][eh*32 + l15]      = pe0;
      fpart[nh][eh*32 + 16 + l15] = pe1;
    }
    __syncthreads();

    if (tid < BE){
      float f = fpart[0][tid] + fpart[1][tid] + A.db4[0];
      int E = E0 + tid;
      A.forcesE[E*3+0] = f * ndS[tid][0];
      A.forcesE[E*3+1] = f * ndS[tid][1];
      A.forcesE[E*3+2] = f * ndS[tid][2];
    }
  } else {
    // ---------------- ANGLE PATH ----------------
    u16 (*XA)[40] = (u16(*)[40])SM;                       // 5120 B
    u16 (*X1)[SX] = (u16(*)[SX])(SM + 5120);              // 17408 B
    float (*geoS)[8] = (float(*)[8])(SM + 22528);         // 2048 B
    float (*fpart)[BE] = (float(*)[BE])(SM + 24576);      // 512 B
    int A0 = (tile - EB) * BE;
    {
      int inst = tid >> 2, q = tid & 3;
      int a = A0 + inst; if (a >= 5*N_RES) a = 0;
      int t = a / N_RES, ri = a - t*N_RES;
      if ((t == 1 || t == 2) && ri >= N_RES-1) ri = 0;
      int i1, i2, i3, central;
      angle_idx(t, ri, i1, i2, i3, central);
      if (q < 3){
        uint4 v = *(const uint4*)(A.nfb + central*24 + q*8);
        *(uint4*)&XA[inst][q*8] = v;
      } else {
        float bax = A.coordsA[i1*3+0]-A.coordsA[i2*3+0];
        float bay = A.coordsA[i1*3+1]-A.coordsA[i2*3+1];
        float baz = A.coordsA[i1*3+2]-A.coordsA[i2*3+2];
        float bcx = A.coordsA[i3*3+0]-A.coordsA[i2*3+0];
        float bcy = A.coordsA[i3*3+1]-A.coordsA[i2*3+1];
        float bcz = A.coordsA[i3*3+2]-A.coordsA[i2*3+2];
        float ban = sqrtf(bax*bax+bay*bay+baz*baz);
        float bcn = sqrtf(bcx*bcx+bcy*bcy+bcz*bcz);
        float cosang = (bax*bcx+bay*bcy+baz*bcz)/(ban*bcn);
        cosang = fminf(fmaxf(cosang, -1.0f+1e-6f), 1.0f-1e-6f);
        float ang = acosf(cosang);
        geoS[inst][0]=bax; geoS[inst][1]=bay; geoS[inst][2]=baz;
        geoS[inst][3]=bcx; geoS[inst][4]=bcy; geoS[inst][5]=bcz;
        geoS[inst][6]=ban; geoS[inst][7]=bcn;
        XA[inst][24] = (u16)f2bf(ang);
        #pragma unroll
        for (int k = 25; k < 32; ++k) XA[inst][k] = 0;
      }
    }
    __syncthreads();

    // Layer 1: K=32, XA -> X1
    #pragma unroll
    for (int mt = 0; mt < 4; ++mt)
      wf[mt][0] = *(const bf16x8*)(A.pa1 + (size_t)((nh*4+mt)*64 + lane)*8);
    #pragma unroll
    for (int mt = 0; mt < 4; ++mt){
      f32x4 b = *(const f32x4*)(A.ab1 + nh*64 + mt*16 + lg*4);
      acc[mt][0] = b; acc[mt][1] = b;
    }
    #pragma unroll
    for (int nt = 0; nt < 2; ++nt){
      bf16x8 x = *(const bf16x8*)&XA[eh*32 + nt*16 + l15][lg*8];
      #pragma unroll
      for (int mt = 0; mt < 4; ++mt)
        acc[mt][nt] = __builtin_amdgcn_mfma_f32_16x16x32_bf16(wf[mt][0], x, acc[mt][nt], 0, 0, 0);
    }
    #pragma unroll
    for (int mt = 0; mt < 4; ++mt)
      #pragma unroll
      for (int nt = 0; nt < 2; ++nt){
        uint2 pk;
        pk.x = cvt_pk_bf16(fast_tanh(acc[mt][nt][0]), fast_tanh(acc[mt][nt][1]));
        pk.y = cvt_pk_bf16(fast_tanh(acc[mt][nt][2]), fast_tanh(acc[mt][nt][3]));
        *(uint2*)&X1[eh*32 + nt*16 + l15][nh*64 + mt*16 + lg*4] = pk;
      }
    __syncthreads();

    // Layer 2: K=128, X1 -> regs
    #pragma unroll
    for (int mt = 0; mt < 4; ++mt)
      #pragma unroll
      for (int ks = 0; ks < 4; ++ks)
        wf[mt][ks] = *(const bf16x8*)(A.pa2 + (size_t)(((nh*4+mt)*4 + ks)*64 + lane)*8);
    #pragma unroll
    for (int mt = 0; mt < 4; ++mt){
      f32x4 b = *(const f32x4*)(A.ab2 + nh*64 + mt*16 + lg*4);
      acc[mt][0] = b; acc[mt][1] = b;
    }
    #pragma unroll
    for (int ks = 0; ks < 4; ++ks)
      #pragma unroll
      for (int nt = 0; nt < 2; ++nt){
        bf16x8 x = *(const bf16x8*)&X1[eh*32 + nt*16 + l15][ks*32 + lg*8];
        #pragma unroll
        for (int mt = 0; mt < 4; ++mt)
          acc[mt][nt] = __builtin_amdgcn_mfma_f32_16x16x32_bf16(wf[mt][ks], x, acc[mt][nt], 0, 0, 0);
      }

    // Output layer
    float pe0 = 0.0f, pe1 = 0.0f;
    #pragma unroll
    for (int mt = 0; mt < 4; ++mt){
      f32x4 w3 = *(const f32x4*)(A.aW3 + nh*64 + mt*16 + lg*4);
      #pragma unroll
      for (int r = 0; r < 4; ++r){
        pe0 += fast_tanh(acc[mt][0][r]) * w3[r];
        pe1 += fast_tanh(acc[mt][1][r]) * w3[r];
      }
    }
    pe0 += __shfl_xor(pe0, 16, 64); pe0 += __shfl_xor(pe0, 32, 64);
    pe1 += __shfl_xor(pe1, 16, 64); pe1 += __shfl_xor(pe1, 32, 64);
    if (lg == 0){
      fpart[nh][eh*32 + l15]      = pe0;
      fpart[nh][eh*32 + 16 + l15] = pe1;
    }
    __syncthreads();

    if (tid < BE){
      int a = A0 + tid;
      bool valid = (a < 5*N_RES);
      int t = valid ? (a / N_RES) : 0;
      int ri = valid ? (a - t*N_RES) : 0;
      if ((t == 1 || t == 2) && ri >= N_RES-1){ valid = false; ri = 0; }
      int i1, i2, i3, central;
      angle_idx(t, ri, i1, i2, i3, central);
      if (valid){
        float af = fpart[0][tid] + fpart[1][tid] + A.ab3[0];
        float bax = geoS[tid][0], bay = geoS[tid][1], baz = geoS[tid][2];
        float bcx = geoS[tid][3], bcy = geoS[tid][4], bcz = geoS[tid][5];
        float ban = geoS[tid][6], bcn = geoS[tid][7];
        float cxx = bay*bcz - baz*bcy;
        float cxy = baz*bcx - bax*bcz;
        float cxz = bax*bcy - bay*bcx;
        float v1x = bay*cxz - baz*cxy;
        float v1y = baz*cxx - bax*cxz;
        float v1z = bax*cxy - bay*cxx;
        float n1 = fmaxf(sqrtf(v1x*v1x+v1y*v1y+v1z*v1z), 1e-12f);
        float fax = af*v1x/(n1*ban);
        float fay = af*v1y/(n1*ban);
        float faz = af*v1z/(n1*ban);
        float v2x = (-bcy)*cxz - (-bcz)*cxy;
        float v2y = (-bcz)*cxx - (-bcx)*cxz;
        float v2z = (-bcx)*cxy - (-bcy)*cxx;
        float n2 = fmaxf(sqrtf(v2x*v2x+v2y*v2y+v2z*v2z), 1e-12f);
        float fcx = af*v2x/(n2*bcn);
        float fcy = af*v2y/(n2*bcn);
        float fcz = af*v2z/(n2*bcn);
        atomicAdd(&A.atom_accs[i1*3+0], fax);
        atomicAdd(&A.atom_accs[i1*3+1], fay);
        atomicAdd(&A.atom_accs[i1*3+2], faz);
        atomicAdd(&A.atom_accs[i2*3+0], -fax-fcx);
        atomicAdd(&A.atom_accs[i2*3+1], -fay-fcy);
        atomicAdd(&A.atom_accs[i2*3+2], -faz-fcz);
        atomicAdd(&A.atom_accs[i3*3+0], fcx);
        atomicAdd(&A.atom_accs[i3*3+1], fcy);
        atomicAdd(&A.atom_accs[i3*3+2], fcz);
      }
    }
  }
}

// ---------------- finish: integrate + next-step position update
__device__ void finish_atoms(const MegaArgs& A, const float* cin, float* cout,
                             int bid, int nb, int tid){
  float dt = A.dtp[0];
  for (int i = bid*256 + tid; i < N_ATOMS; i += nb*256){
    float m = A.masses[i];
    float tx=0.f, ty=0.f, tz=0.f;
    for (int k = 0; k < KNN; ++k){
      const float* fp = A.forcesE + ((size_t)i*KNN + k)*3;
      tx += fp[0]; ty += fp[1]; tz += fp[2];
    }
    float inv = 1.0f/(100.0f*m);
    float ax = tx*inv + A.atom_accs[i*3+0]*inv;
    float ay = ty*inv + A.atom_accs[i*3+1]*inv;
    float az = tz*inv + A.atom_accs[i*3+2]*inv;
    float vx = A.vels[i*3+0] + 0.5f*(A.accs_last[i*3+0]+ax)*dt;
    float vy = A.vels[i*3+1] + 0.5f*(A.accs_last[i*3+1]+ay)*dt;
    float vz = A.vels[i*3+2] + 0.5f*(A.accs_last[i*3+2]+az)*dt;
    A.vels[i*3+0] = vx; A.vels[i*3+1] = vy; A.vels[i*3+2] = vz;
    A.accs_last[i*3+0] = ax; A.accs_last[i*3+1] = ay; A.accs_last[i*3+2] = az;
    cout[i*3+0] = cin[i*3+0] + vx*dt + 0.5f*ax*dt*dt;
    cout[i*3+1] = cin[i*3+1] + vy*dt + 0.5f*ay*dt*dt;
    cout[i*3+2] = cin[i*3+2] + vz*dt + 0.5f*az*dt*dt;
    A.atom_accs[i*3+0] = 0.0f; A.atom_accs[i*3+1] = 0.0f; A.atom_accs[i*3+2] = 0.0f;
  }
}

// ================ the whole simulation as ONE cooperative kernel
__global__ __launch_bounds__(256, 4) void k_mega(MegaArgs A){
  cg::grid_group grid = cg::this_grid();
  __shared__ __align__(16) char SM[36096];
  int tid = threadIdx.x;
  int bid = blockIdx.x;
  int nb  = gridDim.x;

  // phase -1: setup/pack + knn partials (+ step-1 pos update) + loss
  const int NT_FRONT = KNN_TILES + SETUP_TILES + 1;
  for (int t = bid; t < NT_FRONT; t += nb){
    __syncthreads();
    if (t < KNN_TILES)                    knn_tile(A, t, tid, SM);
    else if (t < KNN_TILES + SETUP_TILES) setup_tile(A, t - KNN_TILES, tid);
    else                                  loss_block(A, tid, SM);
  }
  grid.sync();

  // phase 0: KNN merge (graph shared by both steps)
  merge_atoms(A, bid, nb, tid);
  grid.sync();

  // phase 1: step-1 forces
  for (int t = bid; t < EB + AB; t += nb){ __syncthreads(); force_tile(A, t, tid, SM); }
  grid.sync();

  // phase 2: step-1 integrate + step-2 position update (in place)
  finish_atoms(A, A.coordsA, A.coordsA, bid, nb, tid);
  grid.sync();

  // phase 3: step-2 forces
  for (int t = bid; t < EB + AB; t += nb){ __syncthreads(); force_tile(A, t, tid, SM); }
  grid.sync();

  // phase 4: step-2 integrate + step-3 position update -> d_out
  // (reference step 3 is position-update only w.r.t. returned coords)
  finish_atoms(A, A.coordsA, A.out_coords, bid, nb, tid);
}

extern "C" void kernel_launch(void* const* d_in, const int* in_sizes, int n_in,
                              void* d_out, int out_size, void* d_ws, size_t ws_size,
                              hipStream_t stream){
  char* ws = (char*)d_ws;
  float* coordsA   = (float*)ws;                 ws += N_ATOMS*3*sizeof(float);
  float* vels      = (float*)ws;                 ws += N_ATOMS*3*sizeof(float);
  float* accs_last = (float*)ws;                 ws += N_ATOMS*3*sizeof(float);
  float* atom_accs = (float*)ws;                 ws += N_ATOMS*3*sizeof(float);
  float* forcesE   = (float*)ws;                 ws += (size_t)N_EDGES*3*sizeof(float);
  int*   recv      = (int*)ws;                   ws += (size_t)N_EDGES*sizeof(int);
  u32*   keys      = (u32*)ws;                   ws += (size_t)N_ATOMS*NSEG*KSEG*sizeof(u32);
  u16*   nfb       = (u16*)ws;                   ws += (size_t)N_ATOMS*24*sizeof(u16);
  u16*   p1        = (u16*)ws;                   ws += 8192*sizeof(u16);
  u16*   p2        = (u16*)ws;                   ws += 16384*sizeof(u16);
  u16*   p3        = (u16*)ws;                   ws += 16384*sizeof(u16);
  u16*   pa1       = (u16*)ws;                   ws += 4096*sizeof(u16);
  u16*   pa2       = (u16*)ws;                   ws += 16384*sizeof(u16);

  MegaArgs A;
  A.coords_in = (const float*)d_in[0];
  A.node_f    = (const float*)d_in[1];
  A.masses    = (const float*)d_in[3];
  A.vels_in   = (const float*)d_in[4];
  A.dW1 = (const float*)d_in[5];  A.db1 = (const float*)d_in[6];
  A.dW2 = (const float*)d_in[7];  A.db2 = (const float*)d_in[8];
  A.dW3 = (const float*)d_in[9];  A.db3 = (const float*)d_in[10];
  A.dW4 = (const float*)d_in[11]; A.db4 = (const float*)d_in[12];
  A.aW1 = (const float*)d_in[13]; A.ab1 = (const float*)d_in[14];
  A.aW2 = (const float*)d_in[15]; A.ab2 = (const float*)d_in[16];
  A.aW3 = (const float*)d_in[17]; A.ab3 = (const float*)d_in[18];
  A.nsteps = (const int*)d_in[19];
  A.dtp  = (const float*)d_in[20];
  A.temp = (const float*)d_in[21];
  A.coordsA = coordsA; A.vels = vels; A.accs_last = accs_last; A.atom_accs = atom_accs;
  A.keys = keys; A.nfb = nfb;
  A.p1 = p1; A.p2 = p2; A.p3 = p3; A.pa1 = pa1; A.pa2 = pa2;
  A.recv = recv; A.forcesE = forcesE;
  A.out_coords = (float*)d_out;
  A.out_loss   = (float*)d_out + N_ATOMS*3;

  // co-residency: LDS 36 KB -> <=4 blocks/CU; clamp by occupancy query
  int perCU = 0;
  hipOccupancyMaxActiveBlocksPerMultiprocessor(&perCU, k_mega, 256, 0);
  if (perCU < 1) perCU = 1;
  if (perCU > 4) perCU = 4;
  int grid = perCU * 256;   // 256 CUs on MI355X

  void* kp[] = { (void*)&A };
  hipLaunchCooperativeKernel(k_mega, dim3(grid), dim3(256), kp, 0, stream);
}

// Round 13
// 203.619 us; speedup vs baseline: 2.8279x; 2.8279x over previous
//
#include <hip/hip_runtime.h>
#include <math.h>

#define N_ATOMS 8000
#define N_RES   2000
#define KNN     15
#define KSEG    4                // kept per segment (top-4, incl. self in own segment)
#define NSEG    64
#define SEGLEN  (N_ATOMS/NSEG)   // 125
#define N_EDGES (N_ATOMS*KNN)    // 120000
#define BE      64               // edges/instances per MFMA block
#define SX      136              // LDS X row stride (elements)
#define EB      (N_EDGES/BE)     // 1875 edge tiles
#define AB      ((5*N_RES + BE-1)/BE) // 157 angle tiles
#define NB_FORCE 1016            // force blocks; x2 grid-stride = 2032 tiles, <=4/CU resident
#define KNN_BLOCKS 2048          // 32 x-blocks * 64 segments
#define SETUP_ITEMS (24000+192000+8192+16384+16384+4096+16384)  // 277440
#define SETUP_BLOCKS ((SETUP_ITEMS+255)/256)                    // 1084

typedef unsigned long long u64;
typedef unsigned int u32;
typedef unsigned short u16;
typedef __attribute__((ext_vector_type(8))) short bf16x8;
typedef __attribute__((ext_vector_type(4))) float f32x4;

__device__ __forceinline__ float fast_tanh(float x){
  float e = __expf(2.0f*x);
  return 1.0f - 2.0f*__builtin_amdgcn_rcpf(e+1.0f);
}
__device__ __forceinline__ u32 f2bf(float x){
  u32 b = __float_as_uint(x);
  return (b + 0x7FFFu + ((b>>16)&1u)) >> 16;
}
// packed f32x2 -> bf16x2 in one instruction (no builtin on gfx950; RNE like f2bf)
__device__ __forceinline__ u32 cvt_pk_bf16(float lo, float hi){
  u32 d;
  asm("v_cvt_pk_bf16_f32 %0, %1, %2" : "=v"(d) : "v"(lo), "v"(hi));
  return d;
}
__device__ __forceinline__ u32 med3_u32(u32 a, u32 b, u32 c){
  u32 d;
  asm("v_med3_u32 %0, %1, %2, %3" : "=v"(d) : "v"(a), "v"(b), "v"(c));
  return d;
}
__device__ __forceinline__ void angle_idx(int t, int ri, int& i1, int& i2, int& i3, int& central){
  int a1,a2,a3,ar;
  switch (t){
    case 0: a1=0;a2=1;a3=2;ar=0; break;
    case 1: a1=1;a2=2;a3=0;ar=1; break;
    case 2: a1=2;a2=0;a3=1;ar=2; break;
    case 3: a1=0;a2=1;a3=3;ar=0; break;
    default: a1=2;a2=1;a3=3;ar=0; break;
  }
  i1 = ri*4 + a1;
  i2 = (ri + ((ar==2)?1:0))*4 + a2;
  i3 = (ri + ((ar>=1)?1:0))*4 + a3;
  central = (t==1) ? (ri*4+2) : ((t==2) ? ((ri+1)*4) : (ri*4+1));
}

// ================ k_front: fused {knn_part + step-1 pos update} | {setup/pack} | {loss}
__global__ __launch_bounds__(256) void k_front(
    const float* __restrict__ coords_in, const float* __restrict__ vels_in,
    const float* __restrict__ temp, const float* __restrict__ node_f,
    const float* __restrict__ dW1, const float* __restrict__ dW2,
    const float* __restrict__ dW3,
    const float* __restrict__ aW1, const float* __restrict__ aW2,
    const int* __restrict__ nsteps, const float* __restrict__ dtp,
    float* __restrict__ coordsA, float* __restrict__ vels,
    float* __restrict__ accs_last, float* __restrict__ atom_accs,
    u32* __restrict__ keys, u16* __restrict__ nfb,
    u16* __restrict__ p1, u16* __restrict__ p2, u16* __restrict__ p3,
    u16* __restrict__ pa1, u16* __restrict__ pa2,
    float* __restrict__ out_loss)
{
  int bx = blockIdx.x;
  int tid = threadIdx.x;

  if (bx == (int)gridDim.x - 1){
    // ---- loss block
    __shared__ float red[256];
    float s = 0.0f;
    for (int t = tid; t < N_ATOMS*3; t += 256){
      float v = vels_in[t]; s += v*v;
    }
    red[tid] = s; __syncthreads();
    for (int o = 128; o > 0; o >>= 1){
      if (tid < o) red[tid] += red[tid+o];
      __syncthreads();
    }
    if (tid == 0){
      float scale = dtp[0] * (float)nsteps[0] * temp[0];
      out_loss[0] = scale * sqrtf(red[0] / (float)N_ATOMS);
    }
    return;
  }

  if (bx < KNN_BLOCKS){
    // ---- KNN partial: seg = bx>>5, atoms = (bx&31)*256 + tid; keep top-4/segment
    __shared__ __align__(16) float4 sj4[SEGLEN];
    int seg = bx >> 5;
    int j0 = seg*SEGLEN;
    float ts = temp[0];
    float dt = dtp[0];
    if (tid < SEGLEN){
      int j = j0 + tid;
      float x = coords_in[j*3+0] + vels_in[j*3+0]*ts*dt;
      float y = coords_in[j*3+1] + vels_in[j*3+1]*ts*dt;
      float z = coords_in[j*3+2] + vels_in[j*3+2]*ts*dt;
      sj4[tid] = make_float4(x, y, z, 0.0f);
    }
    __syncthreads();
    int atom = (bx & 31)*256 + tid;
    if (atom >= N_ATOMS) return;
    float vx = vels_in[atom*3+0]*ts, vy = vels_in[atom*3+1]*ts, vz = vels_in[atom*3+2]*ts;
    float cx = coords_in[atom*3+0] + vx*dt;
    float cy = coords_in[atom*3+1] + vy*dt;
    float cz = coords_in[atom*3+2] + vz*dt;
    if (seg == 0){
      coordsA[atom*3+0] = cx; coordsA[atom*3+1] = cy; coordsA[atom*3+2] = cz;
      vels[atom*3+0] = vx; vels[atom*3+1] = vy; vels[atom*3+2] = vz;
    }
    u32 b0 = 0xFFFFFFFFu, b1 = 0xFFFFFFFFu, b2 = 0xFFFFFFFFu, b3 = 0xFFFFFFFFu;
    #pragma unroll 5
    for (int t = 0; t < SEGLEN; ++t){
      float4 s = sj4[t];
      float dx = cx - s.x, dy = cy - s.y, dz = cz - s.z;
      float d2 = dx*dx + dy*dy + dz*dz;
      // self included: d2=0 -> global min key, popped (and discarded) at merge r=0
      u32 key = (__float_as_uint(d2) & 0xFFFFE000u) | (u32)(j0 + t);
      b3 = med3_u32(key, b2, b3);
      b2 = med3_u32(key, b1, b2);
      b1 = med3_u32(key, b0, b1);
      b0 = min(b0, key);
    }
    *(uint4*)(keys + ((size_t)atom*NSEG + seg)*KSEG) = make_uint4(b0,b1,b2,b3);
    return;
  }

  // ---- setup/pack blocks
  int t = (bx - KNN_BLOCKS)*256 + tid;
  if (t < 24000){
    accs_last[t] = 0.0f;
    atom_accs[t] = 0.0f;
    return;
  }
  t -= 24000;
  if (t < 192000){ nfb[t] = (u16)f2bf(node_f[t]); return; }
  t -= 192000;
  if (t < 8192){   // dW1: 50x128, K padded to 64 (2 ksteps), 8 mtiles
    int i = t&7, lane = (t>>3)&63, ks = (t>>9)&1, mt = t>>10;
    int n = mt*16 + (lane&15), k = ks*32 + ((lane>>4)&3)*8 + i;
    p1[t] = (k < 50) ? (u16)f2bf(dW1[k*128+n]) : (u16)0;
    return;
  }
  t -= 8192;
  if (t < 16384){  // dW2
    int i = t&7, lane = (t>>3)&63, ks = (t>>9)&3, mt = t>>11;
    int n = mt*16 + (lane&15), k = ks*32 + ((lane>>4)&3)*8 + i;
    p2[t] = (u16)f2bf(dW2[k*128+n]);
    return;
  }
  t -= 16384;
  if (t < 16384){  // dW3
    int i = t&7, lane = (t>>3)&63, ks = (t>>9)&3, mt = t>>11;
    int n = mt*16 + (lane&15), k = ks*32 + ((lane>>4)&3)*8 + i;
    p3[t] = (u16)f2bf(dW3[k*128+n]);
    return;
  }
  t -= 16384;
  if (t < 4096){   // aW1: 25x128 padded to K=32
    int i = t&7, lane = (t>>3)&63, mt = t>>9;
    int n = mt*16 + (lane&15), k = ((lane>>4)&3)*8 + i;
    pa1[t] = (k < 25) ? (u16)f2bf(aW1[k*128+n]) : (u16)0;
    return;
  }
  t -= 4096;
  if (t < 16384){  // aW2
    int i = t&7, lane = (t>>3)&63, ks = (t>>9)&3, mt = t>>11;
    int n = mt*16 + (lane&15), k = ks*32 + ((lane>>4)&3)*8 + i;
    pa2[t] = (u16)f2bf(aW2[k*128+n]);
  }
}

// ================ KNN merge (runs ONCE, graph shared by both steps):
// wave/atom, lane = seg's sorted 4-list in regs, 16 pops (r=0 = self, discarded)
__global__ __launch_bounds__(256) void k_knn_merge(const u32* __restrict__ keys,
                                                   int* __restrict__ recv){
  int w = threadIdx.x >> 6, lane = threadIdx.x & 63;
  int atom = blockIdx.x*4 + w;
  uint4 k4 = *(const uint4*)(keys + (size_t)atom*(NSEG*KSEG) + lane*KSEG);
  u32 c0=k4.x, c1=k4.y, c2=k4.z, c3=k4.w;
  for (int r = 0; r < 16; ++r){
    u32 m = c0;
    #pragma unroll
    for (int off = 1; off < 64; off <<= 1)
      m = min(m, (u32)__shfl_xor((int)m, off, 64));
    if (r > 0 && lane == 0) recv[atom*KNN + (r-1)] = (int)(m & 0x1FFFu);
    u64 win = __ballot(c0 == m);
    int first = (int)__ffsll((unsigned long long)win) - 1;
    if (lane == first){
      c0=c1; c1=c2; c2=c3; c3=0xFFFFFFFFu;
    }
  }
}

// ================ fused force kernel (grid-stride, fully resident):
// tiles [0,EB) = edge MLP, [EB,EB+AB) = angle MLP.
// Edge forces are reduced into per-atom LDS bins and atomicAdd'ed straight into
// atom_accs (same 1/(100m) scaling as angle forces) -- no forcesE buffer.
__global__ __launch_bounds__(256) void k_force(
    const float* __restrict__ coords, const u16* __restrict__ nfb,
    const int* __restrict__ recv,
    const u16* __restrict__ p1, const float* __restrict__ db1,
    const u16* __restrict__ p2, const float* __restrict__ db2,
    const u16* __restrict__ p3, const float* __restrict__ db3,
    const float* __restrict__ dW4, const float* __restrict__ db4,
    const u16* __restrict__ pa1, const float* __restrict__ ab1,
    const u16* __restrict__ pa2, const float* __restrict__ ab2,
    const float* __restrict__ aW3, const float* __restrict__ ab3,
    float* __restrict__ atom_accs)
{
  __shared__ __align__(16) char SM[36224];
  int tid = threadIdx.x;
  int lane = tid & 63;
  int w = tid >> 6;
  int eh = w >> 1, nh = w & 1;
  int l15 = lane & 15, lg = lane >> 4;

  for (int tile = blockIdx.x; tile < EB + AB; tile += NB_FORCE){
  __syncthreads();   // guard LDS reuse across grid-stride iterations

  f32x4 acc[4][2];
  bf16x8 wf[4][4];

  if (tile < EB){
    // ---------------- EDGE PATH ----------------
    u16 (*X0)[SX] = (u16(*)[SX])SM;                       // 17408 B
    u16 (*X1)[SX] = (u16(*)[SX])(SM + 17408);             // 17408 B
    float (*ndS)[3] = (float(*)[3])(SM + 34816);          // 768 B
    float (*fpart)[BE] = (float(*)[BE])(SM + 35584);      // 512 B
    float (*fbin)[3] = (float(*)[3])(SM + 36096);         // 8*3*4 = 96 B
    int E0 = tile * BE;
    int aLo = E0 / 15;

    // ---- stage input features: 4 threads per edge (+ zero force bins)
    {
      if (tid < 24) ((float*)fbin)[tid] = 0.0f;
      int e = tid >> 2, q = tid & 3;
      int E = E0 + e;
      int i = E / 15;
      int r = recv[E];
      if (q < 3){
        int c0 = q*2, c1 = q*2+1;
        int a0 = (c0 < 3) ? i : r, o0 = (c0 % 3)*8;
        int a1 = (c1 < 3) ? i : r, o1 = (c1 % 3)*8;
        uint4 v0 = *(const uint4*)(nfb + a0*24 + o0);
        uint4 v1 = *(const uint4*)(nfb + a1*24 + o1);
        *(uint4*)&X0[e][c0*8] = v0;
        *(uint4*)&X0[e][c1*8] = v1;
      } else {
        float dx = coords[i*3+0] - coords[r*3+0];
        float dy = coords[i*3+1] - coords[r*3+1];
        float dz = coords[i*3+2] - coords[r*3+2];
        float dist = sqrtf(dx*dx + dy*dy + dz*dz);
        float dn = fmaxf(dist, 0.01f);
        ndS[e][0] = dx/dn; ndS[e][1] = dy/dn; ndS[e][2] = dz/dn;
        float seq = fminf(fabsf((float)((i>>2) - (r>>2)))*0.2f, 1.0f);
        X0[e][48] = (u16)f2bf(dist);
        X0[e][49] = (u16)f2bf(seq);
        #pragma unroll
        for (int k = 50; k < 64; k += 2) *(u32*)&X0[e][k] = 0u;
      }
    }
    __syncthreads();

    // Layer 1: K=64, X0 -> X1
    #pragma unroll
    for (int mt = 0; mt < 4; ++mt)
      #pragma unroll
      for (int ks = 0; ks < 2; ++ks)
        wf[mt][ks] = *(const bf16x8*)(p1 + (size_t)(((nh*4+mt)*2 + ks)*64 + lane)*8);
    #pragma unroll
    for (int mt = 0; mt < 4; ++mt){
      f32x4 b = *(const f32x4*)(db1 + nh*64 + mt*16 + lg*4);
      acc[mt][0] = b; acc[mt][1] = b;
    }
    #pragma unroll
    for (int ks = 0; ks < 2; ++ks)
      #pragma unroll
      for (int nt = 0; nt < 2; ++nt){
        bf16x8 x = *(const bf16x8*)&X0[eh*32 + nt*16 + l15][ks*32 + lg*8];
        #pragma unroll
        for (int mt = 0; mt < 4; ++mt)
          acc[mt][nt] = __builtin_amdgcn_mfma_f32_16x16x32_bf16(wf[mt][ks], x, acc[mt][nt], 0, 0, 0);
      }
    #pragma unroll
    for (int mt = 0; mt < 4; ++mt)
      #pragma unroll
      for (int nt = 0; nt < 2; ++nt){
        uint2 pk;
        pk.x = cvt_pk_bf16(fast_tanh(acc[mt][nt][0]), fast_tanh(acc[mt][nt][1]));
        pk.y = cvt_pk_bf16(fast_tanh(acc[mt][nt][2]), fast_tanh(acc[mt][nt][3]));
        *(uint2*)&X1[eh*32 + nt*16 + l15][nh*64 + mt*16 + lg*4] = pk;
      }
    __syncthreads();

    // Layer 2: K=128, X1 -> X0
    #pragma unroll
    for (int mt = 0; mt < 4; ++mt)
      #pragma unroll
      for (int ks = 0; ks < 4; ++ks)
        wf[mt][ks] = *(const bf16x8*)(p2 + (size_t)(((nh*4+mt)*4 + ks)*64 + lane)*8);
    #pragma unroll
    for (int mt = 0; mt < 4; ++mt){
      f32x4 b = *(const f32x4*)(db2 + nh*64 + mt*16 + lg*4);
      acc[mt][0] = b; acc[mt][1] = b;
    }
    #pragma unroll
    for (int ks = 0; ks < 4; ++ks)
      #pragma unroll
      for (int nt = 0; nt < 2; ++nt){
        bf16x8 x = *(const bf16x8*)&X1[eh*32 + nt*16 + l15][ks*32 + lg*8];
        #pragma unroll
        for (int mt = 0; mt < 4; ++mt)
          acc[mt][nt] = __builtin_amdgcn_mfma_f32_16x16x32_bf16(wf[mt][ks], x, acc[mt][nt], 0, 0, 0);
      }
    #pragma unroll
    for (int mt = 0; mt < 4; ++mt)
      #pragma unroll
      for (int nt = 0; nt < 2; ++nt){
        uint2 pk;
        pk.x = cvt_pk_bf16(fast_tanh(acc[mt][nt][0]), fast_tanh(acc[mt][nt][1]));
        pk.y = cvt_pk_bf16(fast_tanh(acc[mt][nt][2]), fast_tanh(acc[mt][nt][3]));
        *(uint2*)&X0[eh*32 + nt*16 + l15][nh*64 + mt*16 + lg*4] = pk;
      }
    __syncthreads();

    // Layer 3: K=128, X0 -> regs
    #pragma unroll
    for (int mt = 0; mt < 4; ++mt)
      #pragma unroll
      for (int ks = 0; ks < 4; ++ks)
        wf[mt][ks] = *(const bf16x8*)(p3 + (size_t)(((nh*4+mt)*4 + ks)*64 + lane)*8);
    #pragma unroll
    for (int mt = 0; mt < 4; ++mt){
      f32x4 b = *(const f32x4*)(db3 + nh*64 + mt*16 + lg*4);
      acc[mt][0] = b; acc[mt][1] = b;
    }
    #pragma unroll
    for (int ks = 0; ks < 4; ++ks)
      #pragma unroll
      for (int nt = 0; nt < 2; ++nt){
        bf16x8 x = *(const bf16x8*)&X0[eh*32 + nt*16 + l15][ks*32 + lg*8];
        #pragma unroll
        for (int mt = 0; mt < 4; ++mt)
          acc[mt][nt] = __builtin_amdgcn_mfma_f32_16x16x32_bf16(wf[mt][ks], x, acc[mt][nt], 0, 0, 0);
      }

    // Layer 4
    float pe0 = 0.0f, pe1 = 0.0f;
    #pragma unroll
    for (int mt = 0; mt < 4; ++mt){
      f32x4 w4 = *(const f32x4*)(dW4 + nh*64 + mt*16 + lg*4);
      #pragma unroll
      for (int r = 0; r < 4; ++r){
        pe0 += fast_tanh(acc[mt][0][r]) * w4[r];
        pe1 += fast_tanh(acc[mt][1][r]) * w4[r];
      }
    }
    pe0 += __shfl_xor(pe0, 16, 64); pe0 += __shfl_xor(pe0, 32, 64);
    pe1 += __shfl_xor(pe1, 16, 64); pe1 += __shfl_xor(pe1, 32, 64);
    if (lg == 0){
      fpart[nh][eh*32 + l15]      = pe0;
      fpart[nh][eh*32 + 16 + l15] = pe1;
    }
    __syncthreads();

    // per-edge force -> per-atom LDS bins
    if (tid < BE){
      float f = fpart[0][tid] + fpart[1][tid] + db4[0];
      int E = E0 + tid;
      int bi = E/15 - aLo;
      atomicAdd(&fbin[bi][0], f * ndS[tid][0]);
      atomicAdd(&fbin[bi][1], f * ndS[tid][1]);
      atomicAdd(&fbin[bi][2], f * ndS[tid][2]);
    }
    __syncthreads();
    if (tid < 18){
      int q = tid/3, c = tid - q*3;
      int a = aLo + q;
      if (a < N_ATOMS) atomicAdd(&atom_accs[a*3 + c], fbin[q][c]);
    }
  } else {
    // ---------------- ANGLE PATH ----------------
    u16 (*XA)[40] = (u16(*)[40])SM;                       // 5120 B
    u16 (*X1)[SX] = (u16(*)[SX])(SM + 5120);              // 17408 B
    float (*geoS)[8] = (float(*)[8])(SM + 22528);         // 2048 B
    float (*fpart)[BE] = (float(*)[BE])(SM + 24576);      // 512 B
    int A0 = (tile - EB) * BE;
    {
      int inst = tid >> 2, q = tid & 3;
      int a = A0 + inst; if (a >= 5*N_RES) a = 0;
      int t = a / N_RES, ri = a - t*N_RES;
      if ((t == 1 || t == 2) && ri >= N_RES-1) ri = 0;
      int i1, i2, i3, central;
      angle_idx(t, ri, i1, i2, i3, central);
      if (q < 3){
        uint4 v = *(const uint4*)(nfb + central*24 + q*8);
        *(uint4*)&XA[inst][q*8] = v;
      } else {
        float bax = coords[i1*3+0]-coords[i2*3+0];
        float bay = coords[i1*3+1]-coords[i2*3+1];
        float baz = coords[i1*3+2]-coords[i2*3+2];
        float bcx = coords[i3*3+0]-coords[i2*3+0];
        float bcy = coords[i3*3+1]-coords[i2*3+1];
        float bcz = coords[i3*3+2]-coords[i2*3+2];
        float ban = sqrtf(bax*bax+bay*bay+baz*baz);
        float bcn = sqrtf(bcx*bcx+bcy*bcy+bcz*bcz);
        float cosang = (bax*bcx+bay*bcy+baz*bcz)/(ban*bcn);
        cosang = fminf(fmaxf(cosang, -1.0f+1e-6f), 1.0f-1e-6f);
        float ang = acosf(cosang);
        geoS[inst][0]=bax; geoS[inst][1]=bay; geoS[inst][2]=baz;
        geoS[inst][3]=bcx; geoS[inst][4]=bcy; geoS[inst][5]=bcz;
        geoS[inst][6]=ban; geoS[inst][7]=bcn;
        XA[inst][24] = (u16)f2bf(ang);
        #pragma unroll
        for (int k = 25; k < 32; ++k) XA[inst][k] = 0;
      }
    }
    __syncthreads();

    // Layer 1: K=32, XA -> X1
    #pragma unroll
    for (int mt = 0; mt < 4; ++mt)
      wf[mt][0] = *(const bf16x8*)(pa1 + (size_t)((nh*4+mt)*64 + lane)*8);
    #pragma unroll
    for (int mt = 0; mt < 4; ++mt){
      f32x4 b = *(const f32x4*)(ab1 + nh*64 + mt*16 + lg*4);
      acc[mt][0] = b; acc[mt][1] = b;
    }
    #pragma unroll
    for (int nt = 0; nt < 2; ++nt){
      bf16x8 x = *(const bf16x8*)&XA[eh*32 + nt*16 + l15][lg*8];
      #pragma unroll
      for (int mt = 0; mt < 4; ++mt)
        acc[mt][nt] = __builtin_amdgcn_mfma_f32_16x16x32_bf16(wf[mt][0], x, acc[mt][nt], 0, 0, 0);
    }
    #pragma unroll
    for (int mt = 0; mt < 4; ++mt)
      #pragma unroll
      for (int nt = 0; nt < 2; ++nt){
        uint2 pk;
        pk.x = cvt_pk_bf16(fast_tanh(acc[mt][nt][0]), fast_tanh(acc[mt][nt][1]));
        pk.y = cvt_pk_bf16(fast_tanh(acc[mt][nt][2]), fast_tanh(acc[mt][nt][3]));
        *(uint2*)&X1[eh*32 + nt*16 + l15][nh*64 + mt*16 + lg*4] = pk;
      }
    __syncthreads();

    // Layer 2: K=128, X1 -> regs
    #pragma unroll
    for (int mt = 0; mt < 4; ++mt)
      #pragma unroll
      for (int ks = 0; ks < 4; ++ks)
        wf[mt][ks] = *(const bf16x8*)(pa2 + (size_t)(((nh*4+mt)*4 + ks)*64 + lane)*8);
    #pragma unroll
    for (int mt = 0; mt < 4; ++mt){
      f32x4 b = *(const f32x4*)(ab2 + nh*64 + mt*16 + lg*4);
      acc[mt][0] = b; acc[mt][1] = b;
    }
    #pragma unroll
    for (int ks = 0; ks < 4; ++ks)
      #pragma unroll
      for (int nt = 0; nt < 2; ++nt){
        bf16x8 x = *(const bf16x8*)&X1[eh*32 + nt*16 + l15][ks*32 + lg*8];
        #pragma unroll
        for (int mt = 0; mt < 4; ++mt)
          acc[mt][nt] = __builtin_amdgcn_mfma_f32_16x16x32_bf16(wf[mt][ks], x, acc[mt][nt], 0, 0, 0);
      }

    // Output layer
    float pe0 = 0.0f, pe1 = 0.0f;
    #pragma unroll
    for (int mt = 0; mt < 4; ++mt){
      f32x4 w3 = *(const f32x4*)(aW3 + nh*64 + mt*16 + lg*4);
      #pragma unroll
      for (int r = 0; r < 4; ++r){
        pe0 += fast_tanh(acc[mt][0][r]) * w3[r];
        pe1 += fast_tanh(acc[mt][1][r]) * w3[r];
      }
    }
    pe0 += __shfl_xor(pe0, 16, 64); pe0 += __shfl_xor(pe0, 32, 64);
    pe1 += __shfl_xor(pe1, 16, 64); pe1 += __shfl_xor(pe1, 32, 64);
    if (lg == 0){
      fpart[nh][eh*32 + l15]      = pe0;
      fpart[nh][eh*32 + 16 + l15] = pe1;
    }
    __syncthreads();

    if (tid < BE){
      int a = A0 + tid;
      bool valid = (a < 5*N_RES);
      int t = valid ? (a / N_RES) : 0;
      int ri = valid ? (a - t*N_RES) : 0;
      if ((t == 1 || t == 2) && ri >= N_RES-1){ valid = false; ri = 0; }
      int i1, i2, i3, central;
      angle_idx(t, ri, i1, i2, i3, central);
      if (valid){
        float af = fpart[0][tid] + fpart[1][tid] + ab3[0];
        float bax = geoS[tid][0], bay = geoS[tid][1], baz = geoS[tid][2];
        float bcx = geoS[tid][3], bcy = geoS[tid][4], bcz = geoS[tid][5];
        float ban = geoS[tid][6], bcn = geoS[tid][7];
        float cxx = bay*bcz - baz*bcy;
        float cxy = baz*bcx - bax*bcz;
        float cxz = bax*bcy - bay*bcx;
        float v1x = bay*cxz - baz*cxy;
        float v1y = baz*cxx - bax*cxz;
        float v1z = bax*cxy - bay*cxx;
        float n1 = fmaxf(sqrtf(v1x*v1x+v1y*v1y+v1z*v1z), 1e-12f);
        float fax = af*v1x/(n1*ban);
        float fay = af*v1y/(n1*ban);
        float faz = af*v1z/(n1*ban);
        float v2x = (-bcy)*cxz - (-bcz)*cxy;
        float v2y = (-bcz)*cxx - (-bcx)*cxz;
        float v2z = (-bcx)*cxy - (-bcy)*cxx;
        float n2 = fmaxf(sqrtf(v2x*v2x+v2y*v2y+v2z*v2z), 1e-12f);
        float fcx = af*v2x/(n2*bcn);
        float fcy = af*v2y/(n2*bcn);
        float fcz = af*v2z/(n2*bcn);
        atomicAdd(&atom_accs[i1*3+0], fax);
        atomicAdd(&atom_accs[i1*3+1], fay);
        atomicAdd(&atom_accs[i1*3+2], faz);
        atomicAdd(&atom_accs[i2*3+0], -fax-fcx);
        atomicAdd(&atom_accs[i2*3+1], -fay-fcy);
        atomicAdd(&atom_accs[i2*3+2], -faz-fcz);
        atomicAdd(&atom_accs[i3*3+0], fcx);
        atomicAdd(&atom_accs[i3*3+1], fcy);
        atomicAdd(&atom_accs[i3*3+2], fcz);
      }
    }
  }
  } // grid-stride tile loop
}

// ================ finish + next-step position update (elementwise; edge+angle
// forces are both already in atom_accs with identical 1/(100m) scaling)
__global__ void k_finish(float* __restrict__ atom_accs,
                         const float* __restrict__ masses, float* __restrict__ vels,
                         float* __restrict__ accs_last,
                         const float* __restrict__ cin, float* __restrict__ cout,
                         const float* __restrict__ dtp){
  int i = blockIdx.x*256 + threadIdx.x;
  if (i >= N_ATOMS) return;
  float dt = dtp[0];
  float inv = 1.0f/(100.0f*masses[i]);
  float ax = atom_accs[i*3+0]*inv;
  float ay = atom_accs[i*3+1]*inv;
  float az = atom_accs[i*3+2]*inv;
  float vx = vels[i*3+0] + 0.5f*(accs_last[i*3+0]+ax)*dt;
  float vy = vels[i*3+1] + 0.5f*(accs_last[i*3+1]+ay)*dt;
  float vz = vels[i*3+2] + 0.5f*(accs_last[i*3+2]+az)*dt;
  vels[i*3+0] = vx; vels[i*3+1] = vy; vels[i*3+2] = vz;
  accs_last[i*3+0] = ax; accs_last[i*3+1] = ay; accs_last[i*3+2] = az;
  cout[i*3+0] = cin[i*3+0] + vx*dt + 0.5f*ax*dt*dt;
  cout[i*3+1] = cin[i*3+1] + vy*dt + 0.5f*ay*dt*dt;
  cout[i*3+2] = cin[i*3+2] + vz*dt + 0.5f*az*dt*dt;
  atom_accs[i*3+0] = 0.0f; atom_accs[i*3+1] = 0.0f; atom_accs[i*3+2] = 0.0f;
}

extern "C" void kernel_launch(void* const* d_in, const int* in_sizes, int n_in,
                              void* d_out, int out_size, void* d_ws, size_t ws_size,
                              hipStream_t stream){
  const float* coords_in = (const float*)d_in[0];
  const float* node_f    = (const float*)d_in[1];
  const float* masses    = (const float*)d_in[3];
  const float* vels_in   = (const float*)d_in[4];
  const float* dW1=(const float*)d_in[5];  const float* db1=(const float*)d_in[6];
  const float* dW2=(const float*)d_in[7];  const float* db2=(const float*)d_in[8];
  const float* dW3=(const float*)d_in[9];  const float* db3=(const float*)d_in[10];
  const float* dW4=(const float*)d_in[11]; const float* db4=(const float*)d_in[12];
  const float* aW1=(const float*)d_in[13]; const float* ab1=(const float*)d_in[14];
  const float* aW2=(const float*)d_in[15]; const float* ab2=(const float*)d_in[16];
  const float* aW3=(const float*)d_in[17]; const float* ab3=(const float*)d_in[18];
  const int*   nsteps=(const int*)d_in[19];
  const float* dtp =(const float*)d_in[20];
  const float* temp=(const float*)d_in[21];

  char* ws = (char*)d_ws;
  float* coordsA   = (float*)ws;                 ws += N_ATOMS*3*sizeof(float);
  float* vels      = (float*)ws;                 ws += N_ATOMS*3*sizeof(float);
  float* accs_last = (float*)ws;                 ws += N_ATOMS*3*sizeof(float);
  float* atom_accs = (float*)ws;                 ws += N_ATOMS*3*sizeof(float);
  int*   recv      = (int*)ws;                   ws += (size_t)N_EDGES*sizeof(int);
  u32*   keys      = (u32*)ws;                   ws += (size_t)N_ATOMS*NSEG*KSEG*sizeof(u32);
  u16*   nfb       = (u16*)ws;                   ws += (size_t)N_ATOMS*24*sizeof(u16);
  u16*   p1        = (u16*)ws;                   ws += 8192*sizeof(u16);
  u16*   p2        = (u16*)ws;                   ws += 16384*sizeof(u16);
  u16*   p3        = (u16*)ws;                   ws += 16384*sizeof(u16);
  u16*   pa1       = (u16*)ws;                   ws += 4096*sizeof(u16);
  u16*   pa2       = (u16*)ws;                   ws += 16384*sizeof(u16);

  float* out_coords = (float*)d_out;
  float* out_loss   = out_coords + N_ATOMS*3;

  // K1: fused setup + knn partials (+ step-1 position update) + loss
  k_front<<<KNN_BLOCKS + SETUP_BLOCKS + 1, 256, 0, stream>>>(
      coords_in, vels_in, temp, node_f, dW1, dW2, dW3, aW1, aW2, nsteps, dtp,
      coordsA, vels, accs_last, atom_accs, keys, nfb, p1, p2, p3, pa1, pa2, out_loss);

  // K2: merge KNN once (graph shared by both force steps)
  k_knn_merge<<<N_ATOMS/4, 256, 0, stream>>>(keys, recv);

  // K3/K4: step 1 forces + integrate
  k_force<<<NB_FORCE, 256, 0, stream>>>(coordsA, nfb, recv,
      p1, db1, p2, db2, p3, db3, dW4, db4,
      pa1, ab1, pa2, ab2, aW3, ab3, atom_accs);
  k_finish<<<(N_ATOMS+255)/256, 256, 0, stream>>>(atom_accs, masses,
      vels, accs_last, coordsA, coordsA, dtp);

  // K5/K6: step 2 forces + integrate; final position update written to d_out
  // (reference step 3 is position-update only w.r.t. returned coords)
  k_force<<<NB_FORCE, 256, 0, stream>>>(coordsA, nfb, recv,
      p1, db1, p2, db2, p3, db3, dW4, db4,
      pa1, ab1, pa2, ab2, aW3, ab3, atom_accs);
  k_finish<<<(N_ATOMS+255)/256, 256, 0, stream>>>(atom_accs, masses,
      vels, accs_last, coordsA, out_coords, dtp);
}